// Round 1
// baseline (252.838 us; speedup 1.0000x reference)
//
#include <hip/hip_runtime.h>
#include <hip/hip_bf16.h>

typedef __bf16 bf16x8 __attribute__((ext_vector_type(8)));
typedef float f32x4 __attribute__((ext_vector_type(4)));

#define W1_STRIDE 200   // 192 + 8 pad -> row = 400B = 100 dwords, %32 = 4
#define W2_STRIDE 136   // 128 + 8 pad -> row = 272B = 68 dwords,  %32 = 4
#define HID_STRIDE 136

// D=64, R=64, H=128, K1=2*64+64=192 fixed by the problem.
__global__ __launch_bounds__(512, 2) void edge_mlp_kernel(
    const float* __restrict__ node_feats,   // [N,64]
    const float* __restrict__ edge_feats,   // [E,64]
    const int* __restrict__ src_idx,        // [E]
    const int* __restrict__ dst_idx,        // [E]
    const float* __restrict__ W1,           // [192,128] row-major
    const float* __restrict__ b1,           // [128]
    const float* __restrict__ W2,           // [128,64]
    const float* __restrict__ b2,           // [64]
    float* __restrict__ out,                // [E,64]
    int E, int nchunks)
{
    __shared__ alignas(16) __bf16 sW1[128 * W1_STRIDE];       // W1^T [h][k]
    __shared__ alignas(16) __bf16 sW2[64 * W2_STRIDE];        // W2^T [r][h]
    __shared__ alignas(16) __bf16 sHid[8 * 16 * HID_STRIDE];  // per-wave [16][136]

    const int tid  = threadIdx.x;
    const int lane = tid & 63;
    const int wid  = tid >> 6;

    // ---- stage W1^T, W2^T in bf16 (once per persistent block) ----
    for (int i = tid; i < 192 * 128; i += 512) {
        int k = i >> 7;       // row of W1
        int h = i & 127;      // col of W1
        sW1[h * W1_STRIDE + k] = (__bf16)W1[i];
    }
    for (int i = tid; i < 128 * 64; i += 512) {
        int k = i >> 6;
        int r = i & 63;
        sW2[r * W2_STRIDE + k] = (__bf16)W2[i];
    }
    __syncthreads();

    const int q   = lane >> 4;     // 0..3
    const int r16 = lane & 15;     // 0..15
    const int ko  = q * 8;         // k-offset within a 32-wide K-step

    // hoist biases (loop-invariant per lane)
    float b1v[8], b2v[4];
#pragma unroll
    for (int n = 0; n < 8; ++n) b1v[n] = b1[n * 16 + r16];
#pragma unroll
    for (int n = 0; n < 4; ++n) b2v[n] = b2[n * 16 + r16];

    __bf16* hid = &sHid[wid * 16 * HID_STRIDE];

    for (int c = blockIdx.x; c < nchunks; c += gridDim.x) {
        const int base = c * 256 + wid * 32;   // 8 waves x 32 edges = 256/chunk
#pragma unroll
        for (int m = 0; m < 2; ++m) {
            const int e  = base + m * 16 + r16;
            const int ec = (e < E) ? e : (E - 1);
            const float* srcp  = node_feats + (size_t)src_idx[ec] * 64;
            const float* dstp  = node_feats + (size_t)dst_idx[ec] * 64;
            const float* edgep = edge_feats + (size_t)ec * 64;

            f32x4 acc1[8];
#pragma unroll
            for (int n = 0; n < 8; ++n) acc1[n] = (f32x4){0.f, 0.f, 0.f, 0.f};

            // ---- GEMM1: [16,192] @ [192,128], K-steps of 32 ----
#pragma unroll
            for (int t = 0; t < 6; ++t) {
                const float* ap;
                if (t < 2)       ap = srcp  + t * 32 + ko;
                else if (t < 4)  ap = dstp  + (t - 2) * 32 + ko;
                else             ap = edgep + (t - 4) * 32 + ko;
                f32x4 a0 = *(const f32x4*)(ap);
                f32x4 a1 = *(const f32x4*)(ap + 4);
                bf16x8 af;
#pragma unroll
                for (int j = 0; j < 4; ++j) {
                    af[j]     = (__bf16)a0[j];
                    af[j + 4] = (__bf16)a1[j];
                }
#pragma unroll
                for (int n = 0; n < 8; ++n) {
                    bf16x8 bf = *(const bf16x8*)&sW1[(n * 16 + r16) * W1_STRIDE + t * 32 + ko];
                    acc1[n] = __builtin_amdgcn_mfma_f32_16x16x32_bf16(af, bf, acc1[n], 0, 0, 0);
                }
            }

            // ---- bias + softplus -> bf16 hidden in per-wave LDS ----
#pragma unroll
            for (int n = 0; n < 8; ++n) {
#pragma unroll
                for (int i = 0; i < 4; ++i) {
                    float x  = acc1[n][i] + b1v[n];
                    float sp = fmaxf(x, 0.0f) + __logf(1.0f + __expf(-fabsf(x)));
                    int row  = q * 4 + i;   // C/D layout: row=(lane>>4)*4+i, col=lane&15
                    hid[row * HID_STRIDE + n * 16 + r16] = (__bf16)sp;
                }
            }
            // wave-private LDS tile: program order within the wave + compiler
            // lgkmcnt waits give us write->read ordering without a barrier.

            // ---- GEMM2: [16,128] @ [128,64] ----
            f32x4 acc2[4];
#pragma unroll
            for (int n = 0; n < 4; ++n) acc2[n] = (f32x4){0.f, 0.f, 0.f, 0.f};
#pragma unroll
            for (int u = 0; u < 4; ++u) {
                bf16x8 a2 = *(const bf16x8*)&hid[r16 * HID_STRIDE + u * 32 + ko];
#pragma unroll
                for (int n = 0; n < 4; ++n) {
                    bf16x8 bf = *(const bf16x8*)&sW2[(n * 16 + r16) * W2_STRIDE + u * 32 + ko];
                    acc2[n] = __builtin_amdgcn_mfma_f32_16x16x32_bf16(a2, bf, acc2[n], 0, 0, 0);
                }
            }

            // ---- epilogue: bias + store ----
#pragma unroll
            for (int i = 0; i < 4; ++i) {
                int erow = base + m * 16 + q * 4 + i;
                if (erow < E) {
                    float* op = out + (size_t)erow * 64 + r16;
#pragma unroll
                    for (int n = 0; n < 4; ++n) {
                        op[n * 16] = acc2[n][i] + b2v[n];
                    }
                }
            }
        }
    }
}

extern "C" void kernel_launch(void* const* d_in, const int* in_sizes, int n_in,
                              void* d_out, int out_size, void* d_ws, size_t ws_size,
                              hipStream_t stream) {
    const float* node_feats = (const float*)d_in[0];
    const float* edge_feats = (const float*)d_in[1];
    const int*   src_idx    = (const int*)d_in[2];
    const int*   dst_idx    = (const int*)d_in[3];
    const float* W1         = (const float*)d_in[4];
    const float* b1         = (const float*)d_in[5];
    const float* W2         = (const float*)d_in[6];
    const float* b2         = (const float*)d_in[7];
    float* out = (float*)d_out;

    const int E = in_sizes[2];           // src_idx element count
    const int nchunks = (E + 255) / 256;
    int grid = nchunks < 256 ? nchunks : 256;

    edge_mlp_kernel<<<grid, 512, 0, stream>>>(node_feats, edge_feats, src_idx, dst_idx,
                                              W1, b1, W2, b2, out, E, nchunks);
}

// Round 2
// 171.680 us; speedup vs baseline: 1.4727x; 1.4727x over previous
//
#include <hip/hip_runtime.h>
#include <hip/hip_bf16.h>

typedef __bf16 bf16x8 __attribute__((ext_vector_type(8)));
typedef float f32x4 __attribute__((ext_vector_type(4)));

#define W1_STRIDE 200   // 192+8 pad: row = 100 dwords, %32=4 -> 8-lane groups spread
#define W2_STRIDE 136   // 128+8 pad: row = 68 dwords, %32=4
#define HID_STRIDE 136

// D=64, R=64, H=128, K1=192 fixed by the problem.
__global__ __launch_bounds__(512, 2) void edge_mlp_kernel(
    const float* __restrict__ node_feats,   // [N,64]
    const float* __restrict__ edge_feats,   // [E,64]
    const int* __restrict__ src_idx,        // [E]
    const int* __restrict__ dst_idx,        // [E]
    const float* __restrict__ W1,           // [192,128]
    const float* __restrict__ b1,           // [128]
    const float* __restrict__ W2,           // [128,64]
    const float* __restrict__ b2,           // [64]
    float* __restrict__ out,                // [E,64]
    int E, int nchunks)
{
    __shared__ alignas(16) __bf16 sW1[128 * W1_STRIDE];          // 51200 B
    __shared__ alignas(16) __bf16 sW2[64 * W2_STRIDE];           // 17408 B
    __shared__ alignas(16) __bf16 sHid[8 * 2 * 16 * HID_STRIDE]; // 69632 B (2 tiles/wave)

    const int tid  = threadIdx.x;
    const int lane = tid & 63;
    const int wid  = tid >> 6;

    // ---- stage W1^T, W2^T in bf16 (once per persistent block) ----
    for (int i = tid; i < 192 * 128; i += 512) {
        int k = i >> 7, h = i & 127;
        sW1[h * W1_STRIDE + k] = (__bf16)W1[i];
    }
    for (int i = tid; i < 128 * 64; i += 512) {
        int k = i >> 6, r = i & 63;
        sW2[r * W2_STRIDE + k] = (__bf16)W2[i];
    }
    __syncthreads();

    const int q   = lane >> 4;
    const int r16 = lane & 15;
    const int ko  = q * 8;

    float b1v[8], b2v[4];
#pragma unroll
    for (int n = 0; n < 8; ++n) b1v[n] = b1[n * 16 + r16];
#pragma unroll
    for (int n = 0; n < 4; ++n) b2v[n] = b2[n * 16 + r16];

    __bf16* hid0 = &sHid[wid * 2 * 16 * HID_STRIDE];
    __bf16* hid1 = hid0 + 16 * HID_STRIDE;

    int c = blockIdx.x;
    // current pair-tile indices (prefetched)
    int is0, id0, is1, id1, ie0, ie1;
    {
        int b = c * 256 + wid * 32;
        int e0 = b + r16, e1 = b + 16 + r16;
        ie0 = e0 < E ? e0 : E - 1;
        ie1 = e1 < E ? e1 : E - 1;
        is0 = src_idx[ie0]; id0 = dst_idx[ie0];
        is1 = src_idx[ie1]; id1 = dst_idx[ie1];
    }

    while (c < nchunks) {
        const int base = c * 256 + wid * 32;
        const float* s0p = node_feats + (size_t)is0 * 64;
        const float* d0p = node_feats + (size_t)id0 * 64;
        const float* e0p = edge_feats + (size_t)ie0 * 64;
        const float* s1p = node_feats + (size_t)is1 * 64;
        const float* d1p = node_feats + (size_t)id1 * 64;
        const float* e1p = edge_feats + (size_t)ie1 * 64;

        // ---- issue all 24 gather loads up front (MLP) ----
        f32x4 g[2][6][2];
#pragma unroll
        for (int t = 0; t < 6; ++t) {
            const float* a0 = (t < 2 ? s0p + t * 32 : t < 4 ? d0p + (t - 2) * 32 : e0p + (t - 4) * 32) + ko;
            const float* a1 = (t < 2 ? s1p + t * 32 : t < 4 ? d1p + (t - 2) * 32 : e1p + (t - 4) * 32) + ko;
            g[0][t][0] = *(const f32x4*)a0;
            g[0][t][1] = *(const f32x4*)(a0 + 4);
            g[1][t][0] = *(const f32x4*)a1;
            g[1][t][1] = *(const f32x4*)(a1 + 4);
        }

        // ---- prefetch next chunk's indices under this chunk's compute ----
        const int cn = c + gridDim.x;
        int nis0 = is0, nid0 = id0, nis1 = is1, nid1 = id1, nie0 = ie0, nie1 = ie1;
        if (cn < nchunks) {
            int b2_ = cn * 256 + wid * 32;
            int e0 = b2_ + r16, e1 = b2_ + 16 + r16;
            nie0 = e0 < E ? e0 : E - 1;
            nie1 = e1 < E ? e1 : E - 1;
            nis0 = src_idx[nie0]; nid0 = dst_idx[nie0];
            nis1 = src_idx[nie1]; nid1 = dst_idx[nie1];
        }

        // ---- convert A-fragments to bf16 ----
        bf16x8 af[2][6];
#pragma unroll
        for (int m = 0; m < 2; ++m)
#pragma unroll
            for (int t = 0; t < 6; ++t)
#pragma unroll
                for (int j = 0; j < 4; ++j) {
                    af[m][t][j]     = (__bf16)g[m][t][0][j];
                    af[m][t][j + 4] = (__bf16)g[m][t][1][j];
                }

        // ---- GEMM1: two 16-row tiles share every B-fragment ----
        f32x4 acc1[2][8];
#pragma unroll
        for (int m = 0; m < 2; ++m)
#pragma unroll
            for (int n = 0; n < 8; ++n) acc1[m][n] = (f32x4){0.f, 0.f, 0.f, 0.f};

        __builtin_amdgcn_s_setprio(1);
#pragma unroll
        for (int t = 0; t < 6; ++t) {
#pragma unroll
            for (int n = 0; n < 8; ++n) {
                bf16x8 bfr = *(const bf16x8*)&sW1[(n * 16 + r16) * W1_STRIDE + t * 32 + ko];
                acc1[0][n] = __builtin_amdgcn_mfma_f32_16x16x32_bf16(af[0][t], bfr, acc1[0][n], 0, 0, 0);
                acc1[1][n] = __builtin_amdgcn_mfma_f32_16x16x32_bf16(af[1][t], bfr, acc1[1][n], 0, 0, 0);
            }
        }
        __builtin_amdgcn_s_setprio(0);

        // ---- bias + softplus -> two bf16 hidden tiles in per-wave LDS ----
#pragma unroll
        for (int n = 0; n < 8; ++n) {
#pragma unroll
            for (int i = 0; i < 4; ++i) {
                float x0  = acc1[0][n][i] + b1v[n];
                float x1  = acc1[1][n][i] + b1v[n];
                float sp0 = fmaxf(x0, 0.f) + __logf(1.f + __expf(-fabsf(x0)));
                float sp1 = fmaxf(x1, 0.f) + __logf(1.f + __expf(-fabsf(x1)));
                int row   = q * 4 + i;   // C/D: row=(lane>>4)*4+i, col=lane&15
                hid0[row * HID_STRIDE + n * 16 + r16] = (__bf16)sp0;
                hid1[row * HID_STRIDE + n * 16 + r16] = (__bf16)sp1;
            }
        }
        // wave-private LDS: program order + compiler lgkmcnt gives write->read ordering

        // ---- GEMM2: B2-fragments shared across the two tiles ----
        f32x4 acc2[2][4];
#pragma unroll
        for (int m = 0; m < 2; ++m)
#pragma unroll
            for (int n = 0; n < 4; ++n) acc2[m][n] = (f32x4){0.f, 0.f, 0.f, 0.f};

        __builtin_amdgcn_s_setprio(1);
#pragma unroll
        for (int u = 0; u < 4; ++u) {
            bf16x8 a20 = *(const bf16x8*)&hid0[r16 * HID_STRIDE + u * 32 + ko];
            bf16x8 a21 = *(const bf16x8*)&hid1[r16 * HID_STRIDE + u * 32 + ko];
#pragma unroll
            for (int n = 0; n < 4; ++n) {
                bf16x8 b2f = *(const bf16x8*)&sW2[(n * 16 + r16) * W2_STRIDE + u * 32 + ko];
                acc2[0][n] = __builtin_amdgcn_mfma_f32_16x16x32_bf16(a20, b2f, acc2[0][n], 0, 0, 0);
                acc2[1][n] = __builtin_amdgcn_mfma_f32_16x16x32_bf16(a21, b2f, acc2[1][n], 0, 0, 0);
            }
        }
        __builtin_amdgcn_s_setprio(0);

        // ---- epilogue: bias + store ----
#pragma unroll
        for (int m = 0; m < 2; ++m) {
#pragma unroll
            for (int i = 0; i < 4; ++i) {
                int erow = base + m * 16 + q * 4 + i;
                if (erow < E) {
                    float* op = out + (size_t)erow * 64 + r16;
#pragma unroll
                    for (int n = 0; n < 4; ++n) {
                        op[n * 16] = acc2[m][n][i] + b2v[n];
                    }
                }
            }
        }

        is0 = nis0; id0 = nid0; is1 = nis1; id1 = nid1; ie0 = nie0; ie1 = nie1;
        c = cn;
    }
}

extern "C" void kernel_launch(void* const* d_in, const int* in_sizes, int n_in,
                              void* d_out, int out_size, void* d_ws, size_t ws_size,
                              hipStream_t stream) {
    const float* node_feats = (const float*)d_in[0];
    const float* edge_feats = (const float*)d_in[1];
    const int*   src_idx    = (const int*)d_in[2];
    const int*   dst_idx    = (const int*)d_in[3];
    const float* W1         = (const float*)d_in[4];
    const float* b1         = (const float*)d_in[5];
    const float* W2         = (const float*)d_in[6];
    const float* b2         = (const float*)d_in[7];
    float* out = (float*)d_out;

    const int E = in_sizes[2];
    const int nchunks = (E + 255) / 256;
    int grid = nchunks < 256 ? nchunks : 256;

    edge_mlp_kernel<<<grid, 512, 0, stream>>>(node_feats, edge_feats, src_idx, dst_idx,
                                              W1, b1, W2, b2, out, E, nchunks);
}